// Round 5
// baseline (5935.530 us; speedup 1.0000x reference)
//
#include <hip/hip_runtime.h>

#define NS    8
#define HGT   128
#define WID   128
#define HW    (HGT * WID)      // 16384
#define BATCH 32
#define EPSV  1e-8f
#define ITERS 20

#define TH   8
#define LH   (TH + 4)          // 12 rows (halo 2 each side)  [legacy path]
#define SH   16                // staged rows for fused path (halo 4 each side)
#define LW   132               // 128 + 2 halo each side

typedef float4 f4;
typedef float2 f2;
typedef _Float16 half4 __attribute__((ext_vector_type(4)));
typedef _Float16 half2v __attribute__((ext_vector_type(2)));

// ---------------------------------------------------------------------------
// Prologue: H0h = fp16(exp(logH)) (into d_out as scratch),
// mrow[b,i,p] = sum_j exp(logH)[b,i,j,p]  (u=v=1 initially).
__global__ __launch_bounds__(256) void k_init(const float* __restrict__ logH,
                                              _Float16* __restrict__ H0h,
                                              float* __restrict__ mrow) {
    int gid = blockIdx.x * 256 + threadIdx.x;   // over VEC/4 = 1,048,576
    int e = gid * 4;
    int p = e & (HW - 1);
    int c = (e >> 14) & 7;
    int b = e >> 17;
    int base = ((b * NS + c) * NS) * HW + p;
    f4 s = {0.f, 0.f, 0.f, 0.f};
#pragma unroll
    for (int j = 0; j < NS; ++j) {
        f4 l = *(const f4*)(logH + base + j * HW);
        f4 ev;
        ev.x = __expf(l.x); ev.y = __expf(l.y);
        ev.z = __expf(l.z); ev.w = __expf(l.w);
        half4 h;
        h.x = (_Float16)ev.x; h.y = (_Float16)ev.y;
        h.z = (_Float16)ev.z; h.w = (_Float16)ev.w;
        *(half4*)(H0h + base + j * HW) = h;
        s.x += ev.x; s.y += ev.y; s.z += ev.z; s.w += ev.w;
    }
    *(f4*)(mrow + e) = s;
}

// 5x5 conv, float2 granule; tc rows indexed r0..r0+4, center col pair lx2.
__device__ __forceinline__ f2 conv5(const float (*tc)[LW], const float* wk,
                                    int r0, int lx2) {
    float s0 = 0.f, s1 = 0.f;
#pragma unroll
    for (int dy = 0; dy < 5; ++dy) {
        const float* row = &tc[r0 + dy][lx2 * 2];   // 8B aligned, 6 floats
        f2 A = *(const f2*)row;
        f2 B = *(const f2*)(row + 2);
        f2 C = *(const f2*)(row + 4);
        float vv[6] = {A.x, A.y, B.x, B.y, C.x, C.y};
#pragma unroll
        for (int dx = 0; dx < 5; ++dx) {
            float w = wk[dy * 5 + dx];
            s0 += w * vv[dx];
            s1 += w * vv[dx + 1];
        }
    }
    return f2{s0, s1};
}

// scalar 5x5 conv at body col hx (tile body starts at col 2 → row[hx+dx]).
__device__ __forceinline__ float conv5s(const float (*tc)[LW], const float* wk,
                                        int r0, int hx) {
    float s = 0.f;
#pragma unroll
    for (int dy = 0; dy < 5; ++dy) {
        const float* row = &tc[r0 + dy][hx];
#pragma unroll
        for (int dx = 0; dx < 5; ++dx) s += wk[dy * 5 + dx] * row[dx];
    }
    return s;
}

// ===========================================================================
// Fused full iteration (row step + col step), one dispatch per iteration.
// Block owns (b, 8 rows). Stages mrow on 16 rows; computes u_new on central 8
// (f2/thread) + 4 halo rows (1 px/thread); builds 12-row mcol tile entirely in
// LDS; smooths it; v_new; col matvec; emits mrow_new. u/v/mrow all ping-pong
// (reads only from _in buffers, writes only to _out) so no cross-block races.
// FIRST=1: u_in = v_in = 1 implicitly (buffers unread).
template <int FIRST>
__global__ __launch_bounds__(512, 4) void k_fused(
        const float* __restrict__ m_in, const float* __restrict__ u_in,
        const float* __restrict__ v_in, float* __restrict__ u_out,
        float* __restrict__ v_out, float* __restrict__ m_out,
        const _Float16* __restrict__ H0h, const float* __restrict__ gk) {
    __shared__ float T[NS][SH][LW];   // mrow: rows 0..15; then mcol: rows 0..11
    __shared__ float wk[25];
    int tid = threadIdx.x;
    int b   = blockIdx.z;
    int ty0 = blockIdx.y * TH;
    if (tid < 25) wk[tid] = gk[tid];

    // ---- stage m_in rows ty0-4 .. ty0+11 (16 rows) x 8 ch
    {
        int r = tid >> 5, q = tid & 31;                 // 512 = 16 rows x 32 f4
        int gh = (ty0 + r - 4 + HGT) & (HGT - 1);
        int er = tid >> 2, ee = tid & 3;                // edge cols: tid < 64
        int egh = (ty0 + er - 4 + HGT) & (HGT - 1);
        int ex  = (ee < 2) ? (126 + ee) : (ee - 2);
        int ehx = (ee < 2) ? ee : (128 + ee);
#pragma unroll
        for (int c = 0; c < NS; ++c) {
            const float* src = m_in + (b * NS + c) * HW;
            f4 val = *(const f4*)(src + gh * WID + q * 4);
            float* dst = &T[c][r][2 + q * 4];
            dst[0] = val.x; dst[1] = val.y; dst[2] = val.z; dst[3] = val.w;
            if (tid < 64) T[c][er][ehx] = src[egh * WID + ex];
        }
    }
    __syncthreads();

    int lx2 = tid & 63, ly = tid >> 6;                  // central: 2 px
    int pc  = (ty0 + ly) * WID + lx2 * 2;
    int hr  = tid >> 7, hx = tid & 127;                 // halo: 1 px
    int hd  = (hr < 2) ? (hr - 2) : (hr + 6);           // -2,-1,+8,+9
    int hgy = (ty0 + hd + HGT) & (HGT - 1);
    int ph  = hgy * WID + hx;
    int htr = (hr < 2) ? (hr + 2) : (hr + 10);          // conv center row (16-row tile)
    int hr2 = (hr < 2) ? hr : (hr + 8);                 // row in 12-row mcol tile

    // ---- phase B: u_new = u/(smooth(mrow)+eps), central + halo
    f2 un[NS]; float unh[NS];
#pragma unroll
    for (int c = 0; c < NS; ++c) {
        f2 s    = conv5(T[c], wk, ly + 2, lx2);         // central row = tile row ly+4
        float sh = conv5s(T[c], wk, htr - 2, hx);
        if (FIRST) {
            un[c].x = 1.f / (s.x + EPSV);
            un[c].y = 1.f / (s.y + EPSV);
            unh[c]  = 1.f / (sh + EPSV);
        } else {
            f2 uo = *(const f2*)(u_in + (b * NS + c) * HW + pc);
            un[c].x = uo.x / (s.x + EPSV);
            un[c].y = uo.y / (s.y + EPSV);
            unh[c]  = u_in[(b * NS + c) * HW + ph] / (sh + EPSV);
        }
        *(f2*)(u_out + (b * NS + c) * HW + pc) = un[c];
    }
    f2 vo[NS]; float voh[NS];
#pragma unroll
    for (int c = 0; c < NS; ++c) {
        if (FIRST) { vo[c] = f2{1.f, 1.f}; voh[c] = 1.f; }
        else {
            vo[c]  = *(const f2*)(v_in + (b * NS + c) * HW + pc);
            voh[c] = v_in[(b * NS + c) * HW + ph];
        }
    }
    __syncthreads();   // all conv reads of mrow tile done; tile may be reused

    // ---- row matvec: mcol = v .* (M^T u_new) on 12 rows, into LDS tile
    const _Float16* Hb = H0h + (size_t)b * NS * NS * HW;
    {
        f2 acc[NS]; float acch[NS];
#pragma unroll
        for (int cp = 0; cp < NS; ++cp) { acc[cp] = f2{0.f, 0.f}; acch[cp] = 0.f; }
#pragma unroll
        for (int c = 0; c < NS; ++c) {
#pragma unroll
            for (int cp = 0; cp < NS; ++cp) {
                int ch = c * NS + cp;
                half2v h = *(const half2v*)(Hb + ch * HW + pc);
                acc[cp].x += (float)h.x * un[c].x;
                acc[cp].y += (float)h.y * un[c].y;
                acch[cp]  += (float)Hb[ch * HW + ph] * unh[c];
            }
        }
#pragma unroll
        for (int cp = 0; cp < NS; ++cp) {
            float mx = vo[cp].x * acc[cp].x;
            float my = vo[cp].y * acc[cp].y;
            float mh = voh[cp] * acch[cp];
            T[cp][ly + 2][2 + lx2 * 2] = mx;            // central rows 2..9
            T[cp][ly + 2][3 + lx2 * 2] = my;
            if (lx2 == 0)  { T[cp][ly + 2][130] = mx; T[cp][ly + 2][131] = my; }
            if (lx2 == 63) { T[cp][ly + 2][0]   = mx; T[cp][ly + 2][1]   = my; }
            T[cp][hr2][2 + hx] = mh;                    // halo rows 0,1,10,11
            if (hx == 0)   T[cp][hr2][130] = mh;
            if (hx == 1)   T[cp][hr2][131] = mh;
            if (hx == 126) T[cp][hr2][0]   = mh;
            if (hx == 127) T[cp][hr2][1]   = mh;
        }
    }
    __syncthreads();

    // ---- phase C: v_new = v/(smooth(mcol)+eps); mrow_new = u_new .* (M v_new)
    f2 vn[NS];
#pragma unroll
    for (int c = 0; c < NS; ++c) {
        f2 sc = conv5(T[c], wk, ly, lx2);               // central mcol row = ly+2
        vn[c].x = vo[c].x / (sc.x + EPSV);
        vn[c].y = vo[c].y / (sc.y + EPSV);
        *(f2*)(v_out + (b * NS + c) * HW + pc) = vn[c];
    }
    {
        f2 acc[NS];
#pragma unroll
        for (int cp = 0; cp < NS; ++cp) acc[cp] = f2{0.f, 0.f};
#pragma unroll
        for (int c = 0; c < NS; ++c) {
#pragma unroll
            for (int cp = 0; cp < NS; ++cp) {
                int ch = cp * NS + c;
                half2v h = *(const half2v*)(Hb + ch * HW + pc);
                acc[cp].x += (float)h.x * vn[c].x;
                acc[cp].y += (float)h.y * vn[c].y;
            }
        }
#pragma unroll
        for (int cp = 0; cp < NS; ++cp) {
            f2 o;
            o.x = un[cp].x * acc[cp].x;
            o.y = un[cp].y * acc[cp].y;
            *(f2*)(m_out + (b * NS + cp) * HW + pc) = o;
        }
    }
}

// ---------------------------------------------------------------------------
// Epilogue: out = exp(logH)*u[i]*v[j] + eps. No H0h read (out clobbers it).
__global__ __launch_bounds__(256) void k_epi(const float* __restrict__ logH,
                                             const float* __restrict__ u,
                                             const float* __restrict__ v,
                                             float* __restrict__ out) {
    int gid = blockIdx.x * 256 + threadIdx.x;   // over VEC/4 (b,i,p4)
    int e = gid * 4;
    int p = e & (HW - 1);
    int i = (e >> 14) & 7;
    int b = e >> 17;
    int base = ((b * NS + i) * NS) * HW + p;
    f4 uu = *(const f4*)(u + e);
#pragma unroll
    for (int j = 0; j < NS; ++j) {
        f4 l  = *(const f4*)(logH + base + j * HW);
        f4 vv = *(const f4*)(v + (b * NS + j) * HW + p);
        f4 o;
        o.x = expf(l.x) * uu.x * vv.x + EPSV;
        o.y = expf(l.y) * uu.y * vv.y + EPSV;
        o.z = expf(l.z) * uu.z * vv.z + EPSV;
        o.w = expf(l.w) * uu.w * vv.w + EPSV;
        *(f4*)(out + base + j * HW) = o;
    }
}

// ===========================================================================
// Legacy path (round-4 proven, 1361 us) — fallback if ws too small.
// ===========================================================================
__device__ __forceinline__ void stage_tile(const float* __restrict__ m_in,
                                           int b, int ty0, int tid,
                                           float tile[NS][LH][LW]) {
#pragma unroll
    for (int c = 0; c < NS; ++c) {
        const float* src = m_in + (b * NS + c) * HW;
        if (tid < LH * 32) {
            int ly = tid >> 5, lxq = tid & 31;
            int gh = (ty0 + ly - 2 + HGT) & (HGT - 1);
            f4 val = *(const f4*)(src + gh * WID + lxq * 4);
            float* dst = &tile[c][ly][2 + lxq * 4];
            dst[0] = val.x; dst[1] = val.y; dst[2] = val.z; dst[3] = val.w;
        } else if (tid >= 512 - LH * 4) {
            int t = tid - (512 - LH * 4);
            int ly = t >> 2, e = t & 3;
            int gh = (ty0 + ly - 2 + HGT) & (HGT - 1);
            int x  = (e < 2) ? (126 + e) : (e - 2);
            int hx = (e < 2) ? e : (128 + e);
            tile[c][ly][hx] = src[gh * WID + x];
        }
    }
}

template <int ROWSTEP, int FIRST>
__global__ __launch_bounds__(512, 4) void k_step(const float* __restrict__ m_in,
                                                 float* __restrict__ a,
                                                 const float* __restrict__ bvec,
                                                 float* __restrict__ m_out,
                                                 const _Float16* __restrict__ H0h,
                                                 const float* __restrict__ gk) {
    __shared__ float tile[NS][LH][LW];
    __shared__ float wk[25];
    int tid = threadIdx.x;
    int b   = blockIdx.z;
    int ty0 = blockIdx.y * TH;
    if (tid < 25) wk[tid] = gk[tid];

    stage_tile(m_in, b, ty0, tid, tile);
    __syncthreads();

    int lx2 = tid & 63;
    int ly  = tid >> 6;
    int p   = (ty0 + ly) * WID + lx2 * 2;

    f2 av[NS];
#pragma unroll
    for (int c = 0; c < NS; ++c) {
        f2 s = conv5(tile[c], wk, ly, lx2);
        int ai = (b * NS + c) * HW + p;
        f2 un;
        if (FIRST) {
            un.x = 1.f / (s.x + EPSV);
            un.y = 1.f / (s.y + EPSV);
        } else {
            f2 ao = *(const f2*)(a + ai);
            un.x = ao.x / (s.x + EPSV);
            un.y = ao.y / (s.y + EPSV);
        }
        *(f2*)(a + ai) = un;
        av[c] = un;
    }

    f2 acc[NS];
#pragma unroll
    for (int cp = 0; cp < NS; ++cp) acc[cp] = f2{0.f, 0.f};
    const _Float16* Hb = H0h + b * NS * NS * HW + p;
#pragma unroll
    for (int c = 0; c < NS; ++c) {
        f2 x = av[c];
#pragma unroll
        for (int cp = 0; cp < NS; ++cp) {
            int ch = ROWSTEP ? (c * NS + cp) : (cp * NS + c);
            half2v h = *(const half2v*)(Hb + ch * HW);
            acc[cp].x += (float)h.x * x.x;
            acc[cp].y += (float)h.y * x.y;
        }
    }
#pragma unroll
    for (int cp = 0; cp < NS; ++cp) {
        int oi = (b * NS + cp) * HW + p;
        f2 o;
        if (ROWSTEP && FIRST) {
            o = acc[cp];
        } else {
            f2 bv = *(const f2*)(bvec + oi);
            o.x = bv.x * acc[cp].x;
            o.y = bv.y * acc[cp].y;
        }
        *(f2*)(m_out + oi) = o;
    }
}

__global__ __launch_bounds__(512, 4) void k_last(const float* __restrict__ m_in,
                                                 const float* __restrict__ v,
                                                 const float* __restrict__ u,
                                                 const float* __restrict__ logH,
                                                 float* __restrict__ out,
                                                 const float* __restrict__ gk) {
    __shared__ float tile[NS][LH][LW];
    __shared__ float wk[25];
    int tid = threadIdx.x;
    int b   = blockIdx.z;
    int ty0 = blockIdx.y * TH;
    if (tid < 25) wk[tid] = gk[tid];

    stage_tile(m_in, b, ty0, tid, tile);
    __syncthreads();

    int lx2 = tid & 63;
    int ly  = tid >> 6;
    int p   = (ty0 + ly) * WID + lx2 * 2;

    f2 av[NS];
#pragma unroll
    for (int c = 0; c < NS; ++c) {
        f2 s = conv5(tile[c], wk, ly, lx2);
        f2 vo = *(const f2*)(v + (b * NS + c) * HW + p);
        av[c].x = vo.x / (s.x + EPSV);
        av[c].y = vo.y / (s.y + EPSV);
    }

    const float* Lb = logH + b * NS * NS * HW + p;
    float* Ob = out + b * NS * NS * HW + p;
#pragma unroll
    for (int i = 0; i < NS; ++i) {
        f2 uu = *(const f2*)(u + (b * NS + i) * HW + p);
#pragma unroll
        for (int j = 0; j < NS; ++j) {
            f2 l = *(const f2*)(Lb + (i * NS + j) * HW);
            f2 o;
            o.x = expf(l.x) * uu.x * av[j].x + EPSV;
            o.y = expf(l.y) * uu.y * av[j].y + EPSV;
            *(f2*)(Ob + (i * NS + j) * HW) = o;
        }
    }
}

// ===========================================================================
extern "C" void kernel_launch(void* const* d_in, const int* in_sizes, int n_in,
                              void* d_out, int out_size, void* d_ws, size_t ws_size,
                              hipStream_t stream) {
    const float* logH = (const float*)d_in[0];
    const float* gk   = (const float*)d_in[1];
    float* out = (float*)d_out;                 // front doubles as H0h scratch
    _Float16* H0h = (_Float16*)d_out;
    float* ws = (float*)d_ws;
    const size_t VEC = (size_t)BATCH * NS * HW; // 4,194,304 floats

    if (ws_size >= 6 * VEC * sizeof(float)) {
        // ---- fused path: 22 dispatches, ping-pong u/v/mrow (101 MB ws) ----
        float* u0 = ws;
        float* u1 = ws + VEC;
        float* v0 = ws + 2 * VEC;
        float* v1 = ws + 3 * VEC;
        float* m0 = ws + 4 * VEC;
        float* m1 = ws + 5 * VEC;
        float* ub[2] = {u0, u1};
        float* vb[2] = {v0, v1};
        float* mb[2] = {m0, m1};

        k_init<<<VEC / 4 / 256, 256, 0, stream>>>(logH, H0h, m0);

        dim3 grid(1, HGT / TH, BATCH);          // 512 blocks x 512 threads
        k_fused<1><<<grid, 512, 0, stream>>>(m0, u0, v0, u1, v1, m1, H0h, gk);
        for (int t = 1; t < ITERS; ++t) {
            int s = t & 1, d = (t + 1) & 1;
            k_fused<0><<<grid, 512, 0, stream>>>(mb[s], ub[s], vb[s],
                                                 ub[d], vb[d], mb[d], H0h, gk);
        }
        // after t=19: results in ub[(ITERS)&1]=u0, vb[...]=v0
        k_epi<<<VEC / 4 / 256, 256, 0, stream>>>(logH, ub[ITERS & 1],
                                                 vb[ITERS & 1], out);
        return;
    }

    // ---- fallback: round-4 proven 41-dispatch path (67 MB ws) ----
    float* u    = ws;
    float* v    = ws + VEC;
    float* mrow = ws + 2 * VEC;
    float* mcol = ws + 3 * VEC;

    k_init<<<VEC / 4 / 256, 256, 0, stream>>>(logH, H0h, mrow);

    dim3 grid(1, HGT / TH, BATCH);
    k_step<1, 1><<<grid, 512, 0, stream>>>(mrow, u, v, mcol, H0h, gk);
    k_step<0, 1><<<grid, 512, 0, stream>>>(mcol, v, u, mrow, H0h, gk);
    for (int it = 1; it < ITERS; ++it) {
        k_step<1, 0><<<grid, 512, 0, stream>>>(mrow, u, v, mcol, H0h, gk);
        if (it != ITERS - 1) {
            k_step<0, 0><<<grid, 512, 0, stream>>>(mcol, v, u, mrow, H0h, gk);
        } else {
            k_last<<<grid, 512, 0, stream>>>(mcol, v, u, logH, out, gk);
        }
    }
}

// Round 7
// 2231.172 us; speedup vs baseline: 2.6603x; 2.6603x over previous
//
#include <hip/hip_runtime.h>

#define NS    8
#define HGT   128
#define WID   128
#define HW    (HGT * WID)      // 16384
#define BATCH 32
#define EPSV  1e-8f
#define ITERS 20

// full-row tiles: 128 wide x 8 tall; 512 threads x 2 pixels each
#define TH   8
#define LH   (TH + 4)          // 12 rows (halo 2 each side)
#define LW   132               // 128 + 2 halo each side

typedef float4 f4;
typedef float2 f2;
typedef _Float16 half8 __attribute__((ext_vector_type(8)));

// ---------------------------------------------------------------------------
// Prologue: H0h[(b*HW+p)*64 + i*8+j] = fp16(exp(logH[b,i,j,p]))  (PIXEL-MAJOR,
// in d_out scratch), mrow[b,i,p] = sum_j exp(logH).  1 pixel per thread.
// u,v are uninitialized — FIRST-specialized steps never read them.
__global__ __launch_bounds__(256) void k_init(const float* __restrict__ logH,
                                              _Float16* __restrict__ H0h,
                                              float* __restrict__ mrow) {
    int gid = blockIdx.x * 256 + threadIdx.x;   // over BATCH*HW = 524,288
    int p = gid & (HW - 1);
    int b = gid >> 14;
    const float* Lb = logH + (size_t)(b * NS * NS) * HW + p;
    _Float16* Hp = H0h + ((size_t)b * HW + p) * (NS * NS);
#pragma unroll
    for (int i = 0; i < NS; ++i) {
        float s = 0.f;
        half8 h;
#pragma unroll
        for (int j = 0; j < NS; ++j) {
            float e = __expf(Lb[(i * NS + j) * HW]);
            h[j] = (_Float16)e;
            s += e;
        }
        *(half8*)(Hp + i * NS) = h;             // 16B aligned contiguous
        mrow[(b * NS + i) * HW + p] = s;
    }
}

// ---------------------------------------------------------------------------
// Stage 8-channel tile of m_in (12 rows x 132 cols, circular) into LDS.
// 512 threads: tid<384 stage the body (f4), last 48 threads do edge cols.
__device__ __forceinline__ void stage_tile(const float* __restrict__ m_in,
                                           int b, int ty0, int tid,
                                           float tile[NS][LH][LW]) {
#pragma unroll
    for (int c = 0; c < NS; ++c) {
        const float* src = m_in + (b * NS + c) * HW;
        if (tid < LH * 32) {                    // 384 threads: 12 rows x 32 f4
            int ly = tid >> 5, lxq = tid & 31;
            int gh = (ty0 + ly - 2 + HGT) & (HGT - 1);
            f4 val = *(const f4*)(src + gh * WID + lxq * 4);
            float* dst = &tile[c][ly][2 + lxq * 4];
            dst[0] = val.x; dst[1] = val.y; dst[2] = val.z; dst[3] = val.w;
        } else if (tid >= 512 - LH * 4) {       // 48 threads: edge columns
            int t = tid - (512 - LH * 4);
            int ly = t >> 2, e = t & 3;
            int gh = (ty0 + ly - 2 + HGT) & (HGT - 1);
            int x  = (e < 2) ? (126 + e) : (e - 2);
            int hx = (e < 2) ? e : (128 + e);
            tile[c][ly][hx] = src[gh * WID + x];
        }
    }
}

// 5x5 conv for a thread's 2 adjacent pixels (float2 granule).
__device__ __forceinline__ f2 conv5(const float (*tc)[LW], const float* wk,
                                    int ly, int lx2) {
    float s0 = 0.f, s1 = 0.f;
#pragma unroll
    for (int dy = 0; dy < 5; ++dy) {
        const float* row = &tc[ly + dy][lx2 * 2];   // 8B aligned, 6 floats
        f2 A = *(const f2*)row;
        f2 B = *(const f2*)(row + 2);
        f2 C = *(const f2*)(row + 4);
        float vv[6] = {A.x, A.y, B.x, B.y, C.x, C.y};
#pragma unroll
        for (int dx = 0; dx < 5; ++dx) {
            float w = wk[dy * 5 + dx];
            s0 += w * vv[dx];
            s1 += w * vv[dx + 1];
        }
    }
    return f2{s0, s1};
}

// ---------------------------------------------------------------------------
// One Sinkhorn half-step: a /= (smooth(m_in)+eps); emit the other marginal
// m_out[c'] = bvec[c'] * sum_c H0h[sel] * a[c].  H0h is PIXEL-MAJOR: per px,
// 64 fp16 channels contiguous (128B = 2 lines); matvec reads 16 x dwordx4
// instead of 64 x dword.  Chunk i holds ch = i*8+j (j=0..7):
//   ROWSTEP=1 (row step): ch = c*8+cp  -> chunk index = c (x), broadcast av[c]
//   ROWSTEP=0 (col step): ch = cp*8+c  -> chunk index = cp (out), dot with av[]
// Accumulation order over c is ascending in both — identical fp sequence to
// the channel-major version.
// FIRST=1: a==1 on input (skip read); additionally bvec==1 when ROWSTEP=1.
template <int ROWSTEP, int FIRST>
__global__ __launch_bounds__(512, 6) void k_step(const float* __restrict__ m_in,
                                                 float* __restrict__ a,
                                                 const float* __restrict__ bvec,
                                                 float* __restrict__ m_out,
                                                 const _Float16* __restrict__ H0h,
                                                 const float* __restrict__ gk) {
    __shared__ float tile[NS][LH][LW];
    __shared__ float wk[25];
    int tid = threadIdx.x;
    int b   = blockIdx.z;
    int ty0 = blockIdx.y * TH;
    if (tid < 25) wk[tid] = gk[tid];

    stage_tile(m_in, b, ty0, tid, tile);
    __syncthreads();

    int lx2 = tid & 63;            // float2 column index 0..63
    int ly  = tid >> 6;            // 0..7
    int p   = (ty0 + ly) * WID + lx2 * 2;

    f2 av[NS];
#pragma unroll
    for (int c = 0; c < NS; ++c) {
        f2 s = conv5(tile[c], wk, ly, lx2);
        int ai = (b * NS + c) * HW + p;
        f2 un;
        if (FIRST) {
            un.x = 1.f / (s.x + EPSV);
            un.y = 1.f / (s.y + EPSV);
        } else {
            f2 ao = *(const f2*)(a + ai);
            un.x = ao.x / (s.x + EPSV);
            un.y = ao.y / (s.y + EPSV);
        }
        *(f2*)(a + ai) = un;
        av[c] = un;
    }

    f2 acc[NS];
#pragma unroll
    for (int cp = 0; cp < NS; ++cp) acc[cp] = f2{0.f, 0.f};
    const _Float16* Hp = H0h + ((size_t)b * HW + p) * (NS * NS);  // px0; px1 at +64
#pragma unroll
    for (int c = 0; c < NS; ++c) {
        half8 h0 = *(const half8*)(Hp + c * NS);            // 16B load, px0
        half8 h1 = *(const half8*)(Hp + NS * NS + c * NS);  // 16B load, px1
        if (ROWSTEP) {
            f2 x = av[c];
#pragma unroll
            for (int cp = 0; cp < NS; ++cp) {
                acc[cp].x += (float)h0[cp] * x.x;
                acc[cp].y += (float)h1[cp] * x.y;
            }
        } else {
#pragma unroll
            for (int j = 0; j < NS; ++j) {
                acc[c].x += (float)h0[j] * av[j].x;
                acc[c].y += (float)h1[j] * av[j].y;
            }
        }
    }
#pragma unroll
    for (int cp = 0; cp < NS; ++cp) {
        int oi = (b * NS + cp) * HW + p;
        f2 o;
        if (ROWSTEP && FIRST) {        // bvec == 1
            o = acc[cp];
        } else {
            f2 bv = *(const f2*)(bvec + oi);
            o.x = bv.x * acc[cp].x;
            o.y = bv.y * acc[cp].y;
        }
        *(f2*)(m_out + oi) = o;
    }
}

// ---------------------------------------------------------------------------
// Last col-step fused with epilogue: vnew = v/(smooth(mcol)+eps) (not stored),
// out[b,i,j,p] = exp(logH)[b,i,j,p] * u[b,i,p] * vnew[b,j,p] + eps.
// Recomputes exp from pristine logH in full fp32 (overwrites the fp16 H0h
// scratch living in d_out — never read here, so no hazard).
__global__ __launch_bounds__(512, 6) void k_last(const float* __restrict__ m_in,
                                                 const float* __restrict__ v,
                                                 const float* __restrict__ u,
                                                 const float* __restrict__ logH,
                                                 float* __restrict__ out,
                                                 const float* __restrict__ gk) {
    __shared__ float tile[NS][LH][LW];
    __shared__ float wk[25];
    int tid = threadIdx.x;
    int b   = blockIdx.z;
    int ty0 = blockIdx.y * TH;
    if (tid < 25) wk[tid] = gk[tid];

    stage_tile(m_in, b, ty0, tid, tile);
    __syncthreads();

    int lx2 = tid & 63;
    int ly  = tid >> 6;
    int p   = (ty0 + ly) * WID + lx2 * 2;

    f2 av[NS];                         // vnew[j]
#pragma unroll
    for (int c = 0; c < NS; ++c) {
        f2 s = conv5(tile[c], wk, ly, lx2);
        f2 vo = *(const f2*)(v + (b * NS + c) * HW + p);
        av[c].x = vo.x / (s.x + EPSV);
        av[c].y = vo.y / (s.y + EPSV);
    }

    const float* Lb = logH + b * NS * NS * HW + p;
    float* Ob = out + b * NS * NS * HW + p;
#pragma unroll
    for (int i = 0; i < NS; ++i) {
        f2 uu = *(const f2*)(u + (b * NS + i) * HW + p);
#pragma unroll
        for (int j = 0; j < NS; ++j) {
            f2 l = *(const f2*)(Lb + (i * NS + j) * HW);
            f2 o;
            o.x = expf(l.x) * uu.x * av[j].x + EPSV;
            o.y = expf(l.y) * uu.y * av[j].y + EPSV;
            *(f2*)(Ob + (i * NS + j) * HW) = o;
        }
    }
}

// ===========================================================================
extern "C" void kernel_launch(void* const* d_in, const int* in_sizes, int n_in,
                              void* d_out, int out_size, void* d_ws, size_t ws_size,
                              hipStream_t stream) {
    const float* logH = (const float*)d_in[0];
    const float* gk   = (const float*)d_in[1];
    float* out = (float*)d_out;                 // front doubles as H0h scratch
    _Float16* H0h = (_Float16*)d_out;           // 67 MB fp16, pixel-major
    float* ws = (float*)d_ws;
    const size_t VEC = (size_t)BATCH * NS * HW; // 4,194,304
    float* u    = ws;
    float* v    = ws + VEC;
    float* mrow = ws + 2 * VEC;
    float* mcol = ws + 3 * VEC;                 // d_ws usage: 67 MB

    k_init<<<BATCH * HW / 256, 256, 0, stream>>>(logH, H0h, mrow);

    dim3 grid(1, HGT / TH, BATCH);              // 512 blocks x 512 threads
    // it = 0: u,v start at 1 — specialized variants skip those reads
    k_step<1, 1><<<grid, 512, 0, stream>>>(mrow, u, v, mcol, H0h, gk);
    k_step<0, 1><<<grid, 512, 0, stream>>>(mcol, v, u, mrow, H0h, gk);
    for (int it = 1; it < ITERS; ++it) {
        // row step: u /= smooth(mrow)+eps; emit mcol = v .* (M^T u)
        k_step<1, 0><<<grid, 512, 0, stream>>>(mrow, u, v, mcol, H0h, gk);
        if (it != ITERS - 1) {
            // col step: v /= smooth(mcol)+eps; emit mrow = u .* (M v)
            k_step<0, 0><<<grid, 512, 0, stream>>>(mcol, v, u, mrow, H0h, gk);
        } else {
            // fused last col step + epilogue (fp32 exp recompute, final write)
            k_last<<<grid, 512, 0, stream>>>(mcol, v, u, logH, out, gk);
        }
    }
}

// Round 9
// 1783.455 us; speedup vs baseline: 3.3281x; 1.2510x over previous
//
#include <hip/hip_runtime.h>

#define NS    8
#define HGT   128
#define WID   128
#define HW    (HGT * WID)      // 16384
#define BATCH 32
#define EPSV  1e-8f
#define ITERS 20

// full-row tiles: 128 wide x 8 tall; 512 threads x 2 pixels each
#define TH   8
#define LH   (TH + 4)          // 12 rows (halo 2 each side)
#define LW   132               // 128 + 2 halo each side

typedef float4 f4;
typedef float2 f2;
typedef _Float16 half4 __attribute__((ext_vector_type(4)));
typedef _Float16 half2v __attribute__((ext_vector_type(2)));

// ---------------------------------------------------------------------------
// Prologue: H0h = fp16(exp(logH)) (into d_out as scratch), CHANNEL-MAJOR
// (same layout as logH; coalesced 8B half4 writes). mrow = sum_j exp(logH).
// u,v buffers are NOT initialized — FIRST-specialized steps never read them.
__global__ __launch_bounds__(256) void k_init(const float* __restrict__ logH,
                                              _Float16* __restrict__ H0h,
                                              float* __restrict__ mrow) {
    int gid = blockIdx.x * 256 + threadIdx.x;   // over VEC/4 = 1,048,576
    int e = gid * 4;
    int p = e & (HW - 1);
    int c = (e >> 14) & 7;
    int b = e >> 17;
    int base = ((b * NS + c) * NS) * HW + p;
    f4 s = {0.f, 0.f, 0.f, 0.f};
#pragma unroll
    for (int j = 0; j < NS; ++j) {
        f4 l = *(const f4*)(logH + base + j * HW);
        f4 ev;
        ev.x = __expf(l.x); ev.y = __expf(l.y);
        ev.z = __expf(l.z); ev.w = __expf(l.w);
        half4 h;
        h.x = (_Float16)ev.x; h.y = (_Float16)ev.y;
        h.z = (_Float16)ev.z; h.w = (_Float16)ev.w;
        *(half4*)(H0h + base + j * HW) = h;
        s.x += ev.x; s.y += ev.y; s.z += ev.z; s.w += ev.w;
    }
    *(f4*)(mrow + e) = s;
}

// ---------------------------------------------------------------------------
// Stage 8-channel tile of m_in (12 rows x 132 cols, circular) into LDS.
// 512 threads: tid<384 stage the body (f4), last 48 threads do edge cols.
__device__ __forceinline__ void stage_tile(const float* __restrict__ m_in,
                                           int b, int ty0, int tid,
                                           float tile[NS][LH][LW]) {
#pragma unroll
    for (int c = 0; c < NS; ++c) {
        const float* src = m_in + (b * NS + c) * HW;
        if (tid < LH * 32) {                    // 384 threads: 12 rows x 32 f4
            int ly = tid >> 5, lxq = tid & 31;
            int gh = (ty0 + ly - 2 + HGT) & (HGT - 1);
            f4 val = *(const f4*)(src + gh * WID + lxq * 4);
            float* dst = &tile[c][ly][2 + lxq * 4];
            dst[0] = val.x; dst[1] = val.y; dst[2] = val.z; dst[3] = val.w;
        } else if (tid >= 512 - LH * 4) {       // 48 threads: edge columns
            int t = tid - (512 - LH * 4);
            int ly = t >> 2, e = t & 3;
            int gh = (ty0 + ly - 2 + HGT) & (HGT - 1);
            int x  = (e < 2) ? (126 + e) : (e - 2);
            int hx = (e < 2) ? e : (128 + e);
            tile[c][ly][hx] = src[gh * WID + x];
        }
    }
}

// 5x5 conv for a thread's 2 adjacent pixels (float2 granule).
__device__ __forceinline__ f2 conv5(const float (*tc)[LW], const float* wk,
                                    int ly, int lx2) {
    float s0 = 0.f, s1 = 0.f;
#pragma unroll
    for (int dy = 0; dy < 5; ++dy) {
        const float* row = &tc[ly + dy][lx2 * 2];   // 8B aligned, 6 floats
        f2 A = *(const f2*)row;
        f2 B = *(const f2*)(row + 2);
        f2 C = *(const f2*)(row + 4);
        float vv[6] = {A.x, A.y, B.x, B.y, C.x, C.y};
#pragma unroll
        for (int dx = 0; dx < 5; ++dx) {
            float w = wk[dy * 5 + dx];
            s0 += w * vv[dx];
            s1 += w * vv[dx + 1];
        }
    }
    return f2{s0, s1};
}

// ---------------------------------------------------------------------------
// One Sinkhorn half-step: a /= (smooth(m_in)+eps); emit the other marginal
// m_out[c'] = bvec[c'] * sum_c H0h[sel] * a[c]   (H0h fp16, channel-major —
// every lane load is a coalesced dword across the wave).
// ROWSTEP=1: a=u, emit over j (ch c*8+cp). ROWSTEP=0: a=v (ch cp*8+c).
// FIRST=1: a==1 on input (skip read); additionally bvec==1 when ROWSTEP=1.
// __launch_bounds__(512,6): VGPR cap 85 -> 3 blocks/CU (LDS 3x50.8KB fits).
template <int ROWSTEP, int FIRST>
__global__ __launch_bounds__(512, 6) void k_step(const float* __restrict__ m_in,
                                                 float* __restrict__ a,
                                                 const float* __restrict__ bvec,
                                                 float* __restrict__ m_out,
                                                 const _Float16* __restrict__ H0h,
                                                 const float* __restrict__ gk) {
    __shared__ float tile[NS][LH][LW];
    __shared__ float wk[25];
    int tid = threadIdx.x;
    int b   = blockIdx.z;
    int ty0 = blockIdx.y * TH;
    if (tid < 25) wk[tid] = gk[tid];

    stage_tile(m_in, b, ty0, tid, tile);
    __syncthreads();

    int lx2 = tid & 63;            // float2 column index 0..63
    int ly  = tid >> 6;            // 0..7
    int p   = (ty0 + ly) * WID + lx2 * 2;

    f2 av[NS];
#pragma unroll
    for (int c = 0; c < NS; ++c) {
        f2 s = conv5(tile[c], wk, ly, lx2);
        int ai = (b * NS + c) * HW + p;
        f2 un;
        if (FIRST) {
            un.x = 1.f / (s.x + EPSV);
            un.y = 1.f / (s.y + EPSV);
        } else {
            f2 ao = *(const f2*)(a + ai);
            un.x = ao.x / (s.x + EPSV);
            un.y = ao.y / (s.y + EPSV);
        }
        *(f2*)(a + ai) = un;
        av[c] = un;
    }

    f2 acc[NS];
#pragma unroll
    for (int cp = 0; cp < NS; ++cp) acc[cp] = f2{0.f, 0.f};
    const _Float16* Hb = H0h + b * NS * NS * HW + p;
#pragma unroll
    for (int c = 0; c < NS; ++c) {
        f2 x = av[c];
#pragma unroll
        for (int cp = 0; cp < NS; ++cp) {
            int ch = ROWSTEP ? (c * NS + cp) : (cp * NS + c);
            half2v h = *(const half2v*)(Hb + ch * HW);
            acc[cp].x += (float)h.x * x.x;
            acc[cp].y += (float)h.y * x.y;
        }
    }
#pragma unroll
    for (int cp = 0; cp < NS; ++cp) {
        int oi = (b * NS + cp) * HW + p;
        f2 o;
        if (ROWSTEP && FIRST) {        // bvec == 1
            o = acc[cp];
        } else {
            f2 bv = *(const f2*)(bvec + oi);
            o.x = bv.x * acc[cp].x;
            o.y = bv.y * acc[cp].y;
        }
        *(f2*)(m_out + oi) = o;
    }
}

// ---------------------------------------------------------------------------
// Last col-step fused with epilogue: vnew = v/(smooth(mcol)+eps) (not stored),
// out[b,i,j,p] = exp(logH)[b,i,j,p] * u[b,i,p] * vnew[b,j,p] + eps.
// Recomputes exp from pristine logH in full fp32 (overwrites the fp16 H0h
// scratch living in d_out — never read here, so no hazard).
__global__ __launch_bounds__(512, 6) void k_last(const float* __restrict__ m_in,
                                                 const float* __restrict__ v,
                                                 const float* __restrict__ u,
                                                 const float* __restrict__ logH,
                                                 float* __restrict__ out,
                                                 const float* __restrict__ gk) {
    __shared__ float tile[NS][LH][LW];
    __shared__ float wk[25];
    int tid = threadIdx.x;
    int b   = blockIdx.z;
    int ty0 = blockIdx.y * TH;
    if (tid < 25) wk[tid] = gk[tid];

    stage_tile(m_in, b, ty0, tid, tile);
    __syncthreads();

    int lx2 = tid & 63;
    int ly  = tid >> 6;
    int p   = (ty0 + ly) * WID + lx2 * 2;

    f2 av[NS];                         // vnew[j]
#pragma unroll
    for (int c = 0; c < NS; ++c) {
        f2 s = conv5(tile[c], wk, ly, lx2);
        f2 vo = *(const f2*)(v + (b * NS + c) * HW + p);
        av[c].x = vo.x / (s.x + EPSV);
        av[c].y = vo.y / (s.y + EPSV);
    }

    const float* Lb = logH + b * NS * NS * HW + p;
    float* Ob = out + b * NS * NS * HW + p;
#pragma unroll
    for (int i = 0; i < NS; ++i) {
        f2 uu = *(const f2*)(u + (b * NS + i) * HW + p);
#pragma unroll
        for (int j = 0; j < NS; ++j) {
            f2 l = *(const f2*)(Lb + (i * NS + j) * HW);
            f2 o;
            o.x = expf(l.x) * uu.x * av[j].x + EPSV;
            o.y = expf(l.y) * uu.y * av[j].y + EPSV;
            *(f2*)(Ob + (i * NS + j) * HW) = o;
        }
    }
}

// ===========================================================================
extern "C" void kernel_launch(void* const* d_in, const int* in_sizes, int n_in,
                              void* d_out, int out_size, void* d_ws, size_t ws_size,
                              hipStream_t stream) {
    const float* logH = (const float*)d_in[0];
    const float* gk   = (const float*)d_in[1];
    float* out = (float*)d_out;                 // front doubles as H0h scratch
    _Float16* H0h = (_Float16*)d_out;           // 67 MB fp16, channel-major
    float* ws = (float*)d_ws;
    const size_t VEC = (size_t)BATCH * NS * HW; // 4,194,304
    float* u    = ws;
    float* v    = ws + VEC;
    float* mrow = ws + 2 * VEC;
    float* mcol = ws + 3 * VEC;                 // d_ws usage: 67 MB

    k_init<<<VEC / 4 / 256, 256, 0, stream>>>(logH, H0h, mrow);

    dim3 grid(1, HGT / TH, BATCH);              // 512 blocks x 512 threads
    // it = 0: u,v start at 1 — specialized variants skip those reads
    k_step<1, 1><<<grid, 512, 0, stream>>>(mrow, u, v, mcol, H0h, gk);
    k_step<0, 1><<<grid, 512, 0, stream>>>(mcol, v, u, mrow, H0h, gk);
    for (int it = 1; it < ITERS; ++it) {
        // row step: u /= smooth(mrow)+eps; emit mcol = v .* (M^T u)
        k_step<1, 0><<<grid, 512, 0, stream>>>(mrow, u, v, mcol, H0h, gk);
        if (it != ITERS - 1) {
            // col step: v /= smooth(mcol)+eps; emit mrow = u .* (M v)
            k_step<0, 0><<<grid, 512, 0, stream>>>(mcol, v, u, mrow, H0h, gk);
        } else {
            // fused last col step + epilogue (fp32 exp recompute, final write)
            k_last<<<grid, 512, 0, stream>>>(mcol, v, u, logH, out, gk);
        }
    }
}